// Round 4
// baseline (184.906 us; speedup 1.0000x reference)
//
#include <hip/hip_runtime.h>
#include <stdint.h>

// Problem constants (B=4096, D=1024 from setup_inputs)
#define BSZ 4096
#define DIM 1024
#define EPSV 1e-6f
#define MARGINV 0.3f
#define LROWS 8
#define GEMM_BLOCKS 528
#define SROWS 8
#define SAMPLE_BLOCKS (BSZ / SROWS)

// ---------------- Threefry-2x32 (bit-exact vs JAX lowering) ----------------
#define TF_ROT(x0, x1, r) { x0 += x1; x1 = ((x1 << r) | (x1 >> (32 - r))); x1 ^= x0; }

__host__ __device__ __forceinline__ void threefry2x32(uint32_t k0, uint32_t k1,
                                                      uint32_t c0, uint32_t c1,
                                                      uint32_t& o0, uint32_t& o1) {
  uint32_t ks2 = k0 ^ k1 ^ 0x1BD11BDAu;
  uint32_t x0 = c0 + k0;
  uint32_t x1 = c1 + k1;
  TF_ROT(x0, x1, 13) TF_ROT(x0, x1, 15) TF_ROT(x0, x1, 26) TF_ROT(x0, x1, 6)
  x0 += k1;  x1 += ks2 + 1u;
  TF_ROT(x0, x1, 17) TF_ROT(x0, x1, 29) TF_ROT(x0, x1, 16) TF_ROT(x0, x1, 24)
  x0 += ks2; x1 += k0 + 2u;
  TF_ROT(x0, x1, 13) TF_ROT(x0, x1, 15) TF_ROT(x0, x1, 26) TF_ROT(x0, x1, 6)
  x0 += k0;  x1 += k1 + 3u;
  TF_ROT(x0, x1, 17) TF_ROT(x0, x1, 29) TF_ROT(x0, x1, 16) TF_ROT(x0, x1, 24)
  x0 += k1;  x1 += ks2 + 4u;
  TF_ROT(x0, x1, 13) TF_ROT(x0, x1, 15) TF_ROT(x0, x1, 26) TF_ROT(x0, x1, 6)
  x0 += ks2; x1 += k0 + 5u;
  o0 = x0; o1 = x1;
}

// ---------------- Kernel 1: norms/sums/nv + fp8 convert + zero acc/ticket ----------------
__global__ __launch_bounds__(256) void prep_kernel(const float* __restrict__ F,
                                                   uint8_t* __restrict__ Fq,
                                                   float* __restrict__ norm2,
                                                   float* __restrict__ sums,
                                                   float* __restrict__ nv,
                                                   float* __restrict__ acc,
                                                   unsigned int* __restrict__ ticket) {
  const int w = threadIdx.x >> 6, l = threadIdx.x & 63;
  const int r = blockIdx.x * 4 + w;  // one wave per row
  const float4* src = (const float4*)(F + (size_t)r * DIM);
  uint32_t* dst = (uint32_t*)(Fq + (size_t)r * DIM);
  float s = 0.f, q = 0.f;
#pragma unroll
  for (int c = 0; c < 4; ++c) {
    float4 v = src[c * 64 + l];
    s += (v.x + v.y) + (v.z + v.w);
    q += v.x * v.x + v.y * v.y + v.z * v.z + v.w * v.w;
    int wd = 0;
    wd = __builtin_amdgcn_cvt_pk_fp8_f32(v.x, v.y, wd, false);  // bytes 0,1
    wd = __builtin_amdgcn_cvt_pk_fp8_f32(v.z, v.w, wd, true);   // bytes 2,3
    dst[c * 64 + l] = (uint32_t)wd;
  }
  for (int off = 32; off; off >>= 1) { s += __shfl_xor(s, off); q += __shfl_xor(q, off); }
  if (l == 0) {
    norm2[r] = q; sums[r] = s;
    nv[r] = q + 2.0f * EPSV * s;
  }
  if (blockIdx.x == 0 && threadIdx.x == 0) { acc[0] = 0.f; ticket[0] = 0u; }
}

// ---------------- Kernel 2: FUSED gemm (fp8 MX, triangle) + sampling ----------------
using int8v = __attribute__((ext_vector_type(8))) int;
using f32x4 = __attribute__((ext_vector_type(4))) float;

__device__ __forceinline__ void async_load16(const void* g, void* l) {
  __builtin_amdgcn_global_load_lds((__attribute__((address_space(1))) void*)g,
                                   (__attribute__((address_space(3))) void*)l, 16, 0, 0);
}

__global__ __launch_bounds__(256) void gemm_sample_kernel(const uint8_t* __restrict__ Fq,
                                                          float* __restrict__ G,
                                                          const int* __restrict__ labels,
                                                          int* __restrict__ pos_idx,
                                                          int* __restrict__ neg_idx,
                                                          uint32_t p0, uint32_t p1,
                                                          uint32_t n0, uint32_t n1) {
  if (blockIdx.x >= GEMM_BLOCKS) {
    // ================= SAMPLE branch: 8 rows per block =================
    __shared__ unsigned long long swp[SROWS], swn[SROWS];
    __shared__ int plist[SROWS][64];
    __shared__ int pcnt[SROWS];
    const int t = threadIdx.x;
    const int i0 = (blockIdx.x - GEMM_BLOCKS) * SROWS;
    if (t < SROWS) { swp[t] = 0ull; swn[t] = 0ull; pcnt[t] = 0; }
    int lj[16];
#pragma unroll
    for (int c = 0; c < 16; ++c) lj[c] = labels[c * 256 + t];
    __syncthreads();
    const uint32_t nt = ~(uint32_t)t;
    const int lane = t & 63;
    for (int r = 0; r < SROWS; ++r) {
      const int li = labels[i0 + r];  // wave-uniform -> scalar
      const uint32_t base = (uint32_t)(i0 + r) * (uint32_t)BSZ + (uint32_t)t;
      unsigned long long bestn = 0ull;
#pragma unroll
      for (int c = 0; c < 16; ++c) {
        uint32_t y0, y1;
        threefry2x32(n0, n1, 0u, base + (uint32_t)(c * 256), y0, y1);
        const uint32_t mant = (y0 ^ y1) >> 9;
        const bool eq = (lj[c] == li);
        if (eq) {  // rare (~8 lanes per row across whole block)
          int sl = atomicAdd(&pcnt[r], 1);
          if (sl < 64) plist[r][sl] = c * 256 + t;
        }
        const uint32_t hi = eq ? 0u : mant;
        const uint32_t lo = eq ? 0u : (nt - (uint32_t)(c * 256));
        const unsigned long long key = ((unsigned long long)hi << 32) | lo;
        if (key > bestn) bestn = key;
      }
      for (int off = 32; off; off >>= 1) {
        unsigned long long o = __shfl_xor(bestn, off);
        if (o > bestn) bestn = o;
      }
      if (lane == 0) atomicMax(&swn[r], bestn);
    }
    __syncthreads();
    // POS: threefry only the actual same-class candidates
    for (int r = 0; r < SROWS; ++r) {
      const int cnt = pcnt[r] < 64 ? pcnt[r] : 64;
      if (t < cnt) {
        const int j = plist[r][t];
        uint32_t y0, y1;
        threefry2x32(p0, p1, 0u, (uint32_t)(i0 + r) * (uint32_t)BSZ + (uint32_t)j, y0, y1);
        const uint32_t mant = (y0 ^ y1) >> 9;
        const unsigned long long key =
            ((unsigned long long)mant << 32) | (uint32_t)(~j);
        atomicMax(&swp[r], key);
      }
    }
    __syncthreads();
    if (t < SROWS) {
      pos_idx[i0 + t] = (int)(~(uint32_t)swp[t]);
      const unsigned long long vn = swn[t];
      neg_idx[i0 + t] = (vn == 0ull) ? 0 : (int)(~(uint32_t)vn);
    }
    return;
  }
  // ================= GEMM branch: fp8 MX K=128, upper-triangle =================
  const int p = blockIdx.x;
  int by = (int)((sqrtf(8.0f * (float)p + 1.0f) - 1.0f) * 0.5f);
  if ((by + 1) * (by + 2) / 2 <= p) ++by;
  if (by * (by + 1) / 2 > p) --by;
  const int bx = p - by * (by + 1) / 2;

  __shared__ __align__(16) uint8_t lA[128 * 128];  // 16 KB
  __shared__ __align__(16) uint8_t lB[128 * 128];
  const int t = threadIdx.x;
  const int l = t & 63;
  const int w = t >> 6;
  const int wm = (w >> 1) * 64;
  const int wn = (w & 1) * 64;
  const int bm = bx * 128;
  const int bn = by * 128;

  f32x4 acc[4][4] = {};

  const int srow = t >> 3;        // 0..31
  const int scol = (t & 7) * 16;  // byte offset within 128-B k-slab
  const uint8_t* gA0 = Fq + (size_t)(bm + srow) * DIM + scol;
  const uint8_t* gB0 = Fq + (size_t)(bn + srow) * DIM + scol;

  for (int it = 0; it < 8; ++it) {  // K = 1024, BK = 128
    const int k0 = it * 128;
    __syncthreads();
#pragma unroll
    for (int ld = 0; ld < 4; ++ld) {
      async_load16(gA0 + (size_t)ld * 32 * DIM + k0, (char*)lA + (ld * 256 + t) * 16);
      async_load16(gB0 + (size_t)ld * 32 * DIM + k0, (char*)lB + (ld * 256 + t) * 16);
    }
    __syncthreads();
    const int fr = l & 15;
    const int fo = (l >> 4) * 32;
    int8v av[4], bv[4];
#pragma unroll
    for (int tm = 0; tm < 4; ++tm) av[tm] = *(const int8v*)&lA[(wm + tm * 16 + fr) * 128 + fo];
#pragma unroll
    for (int tn = 0; tn < 4; ++tn) bv[tn] = *(const int8v*)&lB[(wn + tn * 16 + fr) * 128 + fo];
#pragma unroll
    for (int tm = 0; tm < 4; ++tm)
#pragma unroll
      for (int tn = 0; tn < 4; ++tn)
        acc[tm][tn] = __builtin_amdgcn_mfma_scale_f32_16x16x128_f8f6f4(
            av[tm], bv[tn], acc[tm][tn],
            0, 0,                       // cbsz/blgp = fp8 e4m3
            0, 0x7F7F7F7F,              // scale A = 1.0 (E8M0 127)
            0, 0x7F7F7F7F);             // scale B = 1.0
  }
  // C/D layout: col = lane&15, row = (lane>>4)*4 + reg
  const int cr = (l >> 4) * 4;
  const int cc = l & 15;
#pragma unroll
  for (int tm = 0; tm < 4; ++tm)
#pragma unroll
    for (int tn = 0; tn < 4; ++tn) {
      const int row0 = bm + wm + tm * 16 + cr;
      const int col  = bn + wn + tn * 16 + cc;
#pragma unroll
      for (int r = 0; r < 4; ++r)
        G[(size_t)(row0 + r) * BSZ + col] = acc[tm][tn][r];
      // Mirror tile (G symmetric): 4 consecutive rows -> contiguous float4
      float4 v = make_float4(acc[tm][tn][0], acc[tm][tn][1], acc[tm][tn][2], acc[tm][tn][3]);
      *(float4*)&G[(size_t)col * BSZ + row0] = v;
    }
}

// ---------------- Kernel 3: loss + last-block finalize ----------------
__global__ __launch_bounds__(256) void loss_kernel(const float* __restrict__ G,
                                                   const float* __restrict__ norm2,
                                                   const float* __restrict__ sums,
                                                   const float* __restrict__ nv,
                                                   const int* __restrict__ pos_idx,
                                                   const int* __restrict__ neg_idx,
                                                   float* __restrict__ acc,
                                                   unsigned int* __restrict__ ticket,
                                                   float* __restrict__ out) {
  const int i0 = blockIdx.x * LROWS, t = threadIdx.x;
  const float deps2 = (float)DIM * EPSV * EPSV;
  float ca[LROWS], cb[LROWS];
  const float4* Ga[LROWS];
  const float4* Gb[LROWS];
#pragma unroll
  for (int r = 0; r < LROWS; ++r) {
    const int a = pos_idx[i0 + r], b = neg_idx[i0 + r];
    ca[r] = norm2[a] - 2.0f * EPSV * sums[a] + deps2;
    cb[r] = norm2[b] - 2.0f * EPSV * sums[b] + deps2;
    Ga[r] = (const float4*)(G + (size_t)a * BSZ);
    Gb[r] = (const float4*)(G + (size_t)b * BSZ);
  }
  const float4* N4 = (const float4*)nv;
  float s = 0.f;
#pragma unroll
  for (int c = 0; c < 4; ++c) {
    const int q = c * 256 + t;
    const float4 nj = N4[q];
#pragma unroll
    for (int r = 0; r < LROWS; ++r) {
      const float4 ga = Ga[r][q], gb = Gb[r][q];
      const float capr = ca[r], cbpr = cb[r];
      {
        const float dap = sqrtf(fmaxf(nj.x + capr - 2.f * ga.x, 1e-12f));
        const float dan = sqrtf(fmaxf(nj.x + cbpr - 2.f * gb.x, 1e-12f));
        s += fmaxf(dap - dan + MARGINV, 0.f);
      }
      {
        const float dap = sqrtf(fmaxf(nj.y + capr - 2.f * ga.y, 1e-12f));
        const float dan = sqrtf(fmaxf(nj.y + cbpr - 2.f * gb.y, 1e-12f));
        s += fmaxf(dap - dan + MARGINV, 0.f);
      }
      {
        const float dap = sqrtf(fmaxf(nj.z + capr - 2.f * ga.z, 1e-12f));
        const float dan = sqrtf(fmaxf(nj.z + cbpr - 2.f * gb.z, 1e-12f));
        s += fmaxf(dap - dan + MARGINV, 0.f);
      }
      {
        const float dap = sqrtf(fmaxf(nj.w + capr - 2.f * ga.w, 1e-12f));
        const float dan = sqrtf(fmaxf(nj.w + cbpr - 2.f * gb.w, 1e-12f));
        s += fmaxf(dap - dan + MARGINV, 0.f);
      }
    }
  }
  for (int off = 32; off; off >>= 1) s += __shfl_xor(s, off);
  __shared__ float ps[4];
  const int w = t >> 6, l = t & 63;
  if (l == 0) ps[w] = s;
  __syncthreads();
  if (t == 0) {
    atomicAdd(acc, (ps[0] + ps[1]) + (ps[2] + ps[3]));  // device-scope (m20)
    __threadfence();
    unsigned int old = __hip_atomic_fetch_add(ticket, 1u, __ATOMIC_ACQ_REL,
                                              __HIP_MEMORY_SCOPE_AGENT);
    if (old == (unsigned int)(gridDim.x - 1)) {  // last block finalizes
      float total = __hip_atomic_load(acc, __ATOMIC_ACQUIRE, __HIP_MEMORY_SCOPE_AGENT);
      out[0] = total * (1.0f / ((float)BSZ * (float)BSZ));
    }
  }
}

// ---------------- Launch ----------------
extern "C" void kernel_launch(void* const* d_in, const int* in_sizes, int n_in,
                              void* d_out, int out_size, void* d_ws, size_t ws_size,
                              hipStream_t stream) {
  const float* feat = (const float*)d_in[0];
  const int* labels = (const int*)d_in[1];
  float* out = (float*)d_out;

  char* ws = (char*)d_ws;
  float* G         = (float*)ws;                                  // 64 MB
  uint8_t* Fq      = (uint8_t*)(ws + (size_t)67108864);           // 4 MB
  float* norm2     = (float*)(ws + (size_t)71303168);             // 16 KB
  float* sums      = (float*)(ws + (size_t)71303168 + 16384);     // 16 KB
  float* nv        = (float*)(ws + (size_t)71303168 + 32768);     // 16 KB
  int* pos_idx     = (int*)  (ws + (size_t)71303168 + 49152);     // 16 KB
  int* neg_idx     = (int*)  (ws + (size_t)71303168 + 65536);     // 16 KB
  float* acc       = (float*)(ws + (size_t)71303168 + 81920);     // 4 B
  unsigned int* tk = (unsigned int*)(ws + (size_t)71303168 + 81924);

  // JAX partitionable split: k_i = threefry(base_key=(0,42), (0, i))
  uint32_t k1a, k1b, k2a, k2b;
  threefry2x32(0u, 42u, 0u, 0u, k1a, k1b);  // k1 -> pos uniforms
  threefry2x32(0u, 42u, 0u, 1u, k2a, k2b);  // k2 -> neg uniforms

  prep_kernel<<<dim3(BSZ / 4), dim3(256), 0, stream>>>(feat, Fq, norm2, sums, nv, acc, tk);
  gemm_sample_kernel<<<dim3(GEMM_BLOCKS + SAMPLE_BLOCKS), dim3(256), 0, stream>>>(
      Fq, G, labels, pos_idx, neg_idx, k1a, k1b, k2a, k2b);
  loss_kernel<<<dim3(BSZ / LROWS), dim3(256), 0, stream>>>(G, norm2, sums, nv, pos_idx,
                                                           neg_idx, acc, tk, out);
}

// Round 5
// 168.946 us; speedup vs baseline: 1.0945x; 1.0945x over previous
//
#include <hip/hip_runtime.h>
#include <stdint.h>

// Problem constants (B=4096, D=1024 from setup_inputs)
#define BSZ 4096
#define DIM 1024
#define EPSV 1e-6f
#define MARGINV 0.3f
#define LROWS 8

// ---------------- Threefry-2x32 (bit-exact vs JAX lowering) ----------------
#define TF_ROT(x0, x1, r) { x0 += x1; x1 = ((x1 << r) | (x1 >> (32 - r))); x1 ^= x0; }

__host__ __device__ __forceinline__ void threefry2x32(uint32_t k0, uint32_t k1,
                                                      uint32_t c0, uint32_t c1,
                                                      uint32_t& o0, uint32_t& o1) {
  uint32_t ks2 = k0 ^ k1 ^ 0x1BD11BDAu;
  uint32_t x0 = c0 + k0;
  uint32_t x1 = c1 + k1;
  TF_ROT(x0, x1, 13) TF_ROT(x0, x1, 15) TF_ROT(x0, x1, 26) TF_ROT(x0, x1, 6)
  x0 += k1;  x1 += ks2 + 1u;
  TF_ROT(x0, x1, 17) TF_ROT(x0, x1, 29) TF_ROT(x0, x1, 16) TF_ROT(x0, x1, 24)
  x0 += ks2; x1 += k0 + 2u;
  TF_ROT(x0, x1, 13) TF_ROT(x0, x1, 15) TF_ROT(x0, x1, 26) TF_ROT(x0, x1, 6)
  x0 += k0;  x1 += k1 + 3u;
  TF_ROT(x0, x1, 17) TF_ROT(x0, x1, 29) TF_ROT(x0, x1, 16) TF_ROT(x0, x1, 24)
  x0 += k1;  x1 += ks2 + 4u;
  TF_ROT(x0, x1, 13) TF_ROT(x0, x1, 15) TF_ROT(x0, x1, 26) TF_ROT(x0, x1, 6)
  x0 += ks2; x1 += k0 + 5u;
  o0 = x0; o1 = x1;
}

__device__ __forceinline__ uint16_t f2bf(float f) {  // RNE float->bf16
  uint32_t u = __float_as_uint(f);
  u += 0x7FFFu + ((u >> 16) & 1u);
  return (uint16_t)(u >> 16);
}

// ---------------- Kernel 1: norms/sums/nv + fp8 convert + zero acc/ticket ----------------
__global__ __launch_bounds__(256) void prep_kernel(const float* __restrict__ F,
                                                   uint8_t* __restrict__ Fq,
                                                   float* __restrict__ norm2,
                                                   float* __restrict__ sums,
                                                   float* __restrict__ nv,
                                                   float* __restrict__ acc,
                                                   unsigned int* __restrict__ ticket) {
  const int w = threadIdx.x >> 6, l = threadIdx.x & 63;
  const int r = blockIdx.x * 4 + w;  // one wave per row
  const float4* src = (const float4*)(F + (size_t)r * DIM);
  uint32_t* dst = (uint32_t*)(Fq + (size_t)r * DIM);
  float s = 0.f, q = 0.f;
#pragma unroll
  for (int c = 0; c < 4; ++c) {
    float4 v = src[c * 64 + l];
    s += (v.x + v.y) + (v.z + v.w);
    q += v.x * v.x + v.y * v.y + v.z * v.z + v.w * v.w;
    int wd = 0;
    wd = __builtin_amdgcn_cvt_pk_fp8_f32(v.x, v.y, wd, false);  // bytes 0,1
    wd = __builtin_amdgcn_cvt_pk_fp8_f32(v.z, v.w, wd, true);   // bytes 2,3
    dst[c * 64 + l] = (uint32_t)wd;
  }
  for (int off = 32; off; off >>= 1) { s += __shfl_xor(s, off); q += __shfl_xor(q, off); }
  if (l == 0) {
    norm2[r] = q; sums[r] = s;
    nv[r] = q + 2.0f * EPSV * s;
  }
  if (blockIdx.x == 0 && threadIdx.x == 0) { acc[0] = 0.f; ticket[0] = 0u; }
}

// ---------------- Kernel 2: triplet mining (1 row/block, candidate-list pos) ----------------
// NEG: one threefry per pair, 32-bit lane-local argmax key (mant<<4)|(15-c)
//      (tie -> lower c = lower j within lane); cross-lane via 64-bit (mant<<32)|~j.
// POS: same-label js pushed to LDS list during neg scan (~8/row), tiny second phase.
__global__ __launch_bounds__(256) void sample_kernel(const int* __restrict__ labels,
                                                     int* __restrict__ pos_idx,
                                                     int* __restrict__ neg_idx,
                                                     uint32_t p0, uint32_t p1,
                                                     uint32_t n0, uint32_t n1) {
  __shared__ int plist[64];
  __shared__ int pcnt;
  __shared__ unsigned long long swp;
  __shared__ unsigned long long swn[4];
  const int i = blockIdx.x, t = threadIdx.x;
  if (t == 0) { pcnt = 0; swp = 0ull; }
  int lj[16];
#pragma unroll
  for (int c = 0; c < 16; ++c) lj[c] = labels[c * 256 + t];
  const int li = labels[i];  // wave-uniform -> scalar
  __syncthreads();
  const uint32_t base = (uint32_t)i * (uint32_t)BSZ + (uint32_t)t;
  uint32_t bestn = 0u;
#pragma unroll
  for (int c = 0; c < 16; ++c) {
    uint32_t y0, y1;
    threefry2x32(n0, n1, 0u, base + (uint32_t)(c * 256), y0, y1);
    const uint32_t pack = (((y0 ^ y1) >> 9) << 4) | (uint32_t)(15 - c);
    const bool eq = (lj[c] == li);
    if (eq) {  // rare: ~8 lanes total per block
      int sl = atomicAdd(&pcnt, 1);
      if (sl < 64) plist[sl] = c * 256 + t;
    }
    const uint32_t v = eq ? 0u : pack;
    if (v > bestn) bestn = v;
  }
  // lane-local 32-bit -> global 64-bit key
  unsigned long long keyn = 0ull;
  if (bestn) {
    const int c = 15 - (int)(bestn & 15u);
    const int j = c * 256 + t;
    keyn = ((unsigned long long)(bestn >> 4) << 32) | (uint32_t)(~j);
  }
  for (int off = 32; off; off >>= 1) {
    unsigned long long o = __shfl_xor(keyn, off);
    if (o > keyn) keyn = o;
  }
  const int w = t >> 6, lane = t & 63;
  if (lane == 0) swn[w] = keyn;
  __syncthreads();  // also fences plist/pcnt
  const int cnt = pcnt < 64 ? pcnt : 64;
  if (t < cnt) {
    const int j = plist[t];
    uint32_t y0, y1;
    threefry2x32(p0, p1, 0u, (uint32_t)i * (uint32_t)BSZ + (uint32_t)j, y0, y1);
    const unsigned long long key =
        ((unsigned long long)((y0 ^ y1) >> 9) << 32) | (uint32_t)(~j);
    atomicMax(&swp, key);
  }
  __syncthreads();
  if (t == 0) {
    unsigned long long vn = swn[0];
#pragma unroll
    for (int qd = 1; qd < 4; ++qd) if (swn[qd] > vn) vn = swn[qd];
    neg_idx[i] = (vn == 0ull) ? 0 : (int)(~(uint32_t)vn);
    pos_idx[i] = (int)(~(uint32_t)swp);  // i itself always matches -> swp != 0
  }
}

// ---------------- Kernel 3: G = Fq * Fq^T, fp8 MX K=128, triangle, bf16 out ----------------
using int8v = __attribute__((ext_vector_type(8))) int;
using int4v = __attribute__((ext_vector_type(4))) int;
using f32x4 = __attribute__((ext_vector_type(4))) float;

__device__ __forceinline__ void async_load16(const void* g, void* l) {
  __builtin_amdgcn_global_load_lds((__attribute__((address_space(1))) void*)g,
                                   (__attribute__((address_space(3))) void*)l, 16, 0, 0);
}

// LDS layout: row r (128 B) holds 8 chunks of 16 B; chunk c stored at slot c ^ (r & 7).
// Staging (dest = wave-uniform base + lane*16) realizes this by permuting the GLOBAL
// source chunk per lane: lane t loads chunk (t&7) ^ ((t>>3)&7) of row t>>3.
__global__ __launch_bounds__(256) void gemm_kernel(const uint8_t* __restrict__ Fq,
                                                   uint16_t* __restrict__ Gb) {
  // Triangular block decode: p = by*(by+1)/2 + bx, bx <= by  (32x32 block grid)
  const int p = blockIdx.x;
  int by = (int)((sqrtf(8.0f * (float)p + 1.0f) - 1.0f) * 0.5f);
  if ((by + 1) * (by + 2) / 2 <= p) ++by;
  if (by * (by + 1) / 2 > p) --by;
  const int bx = p - by * (by + 1) / 2;

  __shared__ __align__(16) uint8_t lA[128 * 128];  // 16 KB
  __shared__ __align__(16) uint8_t lB[128 * 128];
  const int t = threadIdx.x;
  const int l = t & 63;
  const int w = t >> 6;
  const int wm = (w >> 1) * 64;
  const int wn = (w & 1) * 64;
  const int bm = bx * 128;
  const int bn = by * 128;

  f32x4 acc[4][4] = {};

  const int srow = t >> 3;  // 0..31
  const int scol = (((t & 7) ^ ((t >> 3) & 7)) << 4);  // XOR-swizzled source chunk
  const uint8_t* gA0 = Fq + (size_t)(bm + srow) * DIM + scol;
  const uint8_t* gB0 = Fq + (size_t)(bn + srow) * DIM + scol;

  // Fragment LDS byte offsets (iteration-invariant): row fra, chunks c0, c0+1
  const int fr = l & 15;
  const int c0 = (l >> 4) * 2;
  int offA[4][2], offB[4][2];
#pragma unroll
  for (int tm = 0; tm < 4; ++tm) {
    const int fra = wm + tm * 16 + fr, sw = fra & 7;
    offA[tm][0] = fra * 128 + ((c0 ^ sw) << 4);
    offA[tm][1] = fra * 128 + (((c0 + 1) ^ sw) << 4);
    const int frb = wn + tm * 16 + fr, sb = frb & 7;
    offB[tm][0] = frb * 128 + ((c0 ^ sb) << 4);
    offB[tm][1] = frb * 128 + (((c0 + 1) ^ sb) << 4);
  }

  for (int it = 0; it < 8; ++it) {  // K = 1024, BK = 128
    const int k0 = it * 128;
    __syncthreads();
#pragma unroll
    for (int ld = 0; ld < 4; ++ld) {
      async_load16(gA0 + (size_t)ld * 32 * DIM + k0, (char*)lA + (ld * 256 + t) * 16);
      async_load16(gB0 + (size_t)ld * 32 * DIM + k0, (char*)lB + (ld * 256 + t) * 16);
    }
    __syncthreads();
    int8v av[4], bv[4];
#pragma unroll
    for (int tm = 0; tm < 4; ++tm) {
      int4v alo = *(const int4v*)&lA[offA[tm][0]];
      int4v ahi = *(const int4v*)&lA[offA[tm][1]];
      av[tm] = __builtin_shufflevector(alo, ahi, 0, 1, 2, 3, 4, 5, 6, 7);
      int4v blo = *(const int4v*)&lB[offB[tm][0]];
      int4v bhi = *(const int4v*)&lB[offB[tm][1]];
      bv[tm] = __builtin_shufflevector(blo, bhi, 0, 1, 2, 3, 4, 5, 6, 7);
    }
#pragma unroll
    for (int tm = 0; tm < 4; ++tm)
#pragma unroll
      for (int tn = 0; tn < 4; ++tn)
        acc[tm][tn] = __builtin_amdgcn_mfma_scale_f32_16x16x128_f8f6f4(
            av[tm], bv[tn], acc[tm][tn],
            0, 0,                       // cbsz/blgp = fp8 e4m3
            0, 0x7F7F7F7F,              // scale A = 1.0 (E8M0 127)
            0, 0x7F7F7F7F);             // scale B = 1.0
  }
  // C/D layout: col = lane&15, row = (lane>>4)*4 + reg
  const int cr = (l >> 4) * 4;
  const int cc = l & 15;
#pragma unroll
  for (int tm = 0; tm < 4; ++tm)
#pragma unroll
    for (int tn = 0; tn < 4; ++tn) {
      const int row0 = bm + wm + tm * 16 + cr;
      const int col  = bn + wn + tn * 16 + cc;
      ushort h0 = f2bf(acc[tm][tn][0]), h1 = f2bf(acc[tm][tn][1]);
      ushort h2 = f2bf(acc[tm][tn][2]), h3 = f2bf(acc[tm][tn][3]);
      Gb[(size_t)(row0 + 0) * BSZ + col] = h0;
      Gb[(size_t)(row0 + 1) * BSZ + col] = h1;
      Gb[(size_t)(row0 + 2) * BSZ + col] = h2;
      Gb[(size_t)(row0 + 3) * BSZ + col] = h3;
      // Mirror tile (G symmetric): 4 consecutive rows -> contiguous ushort4 (8 B)
      ushort4 v = make_ushort4(h0, h1, h2, h3);
      *(ushort4*)&Gb[(size_t)col * BSZ + row0] = v;  // row0 4-aligned -> 8B aligned
    }
}

// ---------------- Kernel 4: loss (bf16 G) + last-block finalize ----------------
__device__ __forceinline__ float bfl(uint32_t w) { return __uint_as_float(w << 16); }
__device__ __forceinline__ float bfh(uint32_t w) { return __uint_as_float(w & 0xFFFF0000u); }

__global__ __launch_bounds__(256) void loss_kernel(const uint16_t* __restrict__ Gb,
                                                   const float* __restrict__ norm2,
                                                   const float* __restrict__ sums,
                                                   const float* __restrict__ nv,
                                                   const int* __restrict__ pos_idx,
                                                   const int* __restrict__ neg_idx,
                                                   float* __restrict__ acc,
                                                   unsigned int* __restrict__ ticket,
                                                   float* __restrict__ out) {
  const int i0 = blockIdx.x * LROWS, t = threadIdx.x;
  const float deps2 = (float)DIM * EPSV * EPSV;
  float ca[LROWS], cb[LROWS];
  const uint4* Ga[LROWS];
  const uint4* Gn[LROWS];
#pragma unroll
  for (int r = 0; r < LROWS; ++r) {
    const int a = pos_idx[i0 + r], b = neg_idx[i0 + r];
    ca[r] = norm2[a] - 2.0f * EPSV * sums[a] + deps2;
    cb[r] = norm2[b] - 2.0f * EPSV * sums[b] + deps2;
    Ga[r] = (const uint4*)(Gb + (size_t)a * BSZ);
    Gn[r] = (const uint4*)(Gb + (size_t)b * BSZ);
  }
  const float4* N4 = (const float4*)nv;
  float s = 0.f;
#pragma unroll
  for (int c = 0; c < 2; ++c) {
    const int q = c * 256 + t;          // uint4 index: 8 bf16 entries
    const float4 nva = N4[q * 2];       // nv[j0..j0+3]
    const float4 nvb = N4[q * 2 + 1];   // nv[j0+4..j0+7]
    float nj[8] = {nva.x, nva.y, nva.z, nva.w, nvb.x, nvb.y, nvb.z, nvb.w};
#pragma unroll
    for (int r = 0; r < LROWS; ++r) {
      const uint4 ga = Ga[r][q], gn = Gn[r][q];
      const float capr = ca[r], cbpr = cb[r];
      float gav[8] = {bfl(ga.x), bfh(ga.x), bfl(ga.y), bfh(ga.y),
                      bfl(ga.z), bfh(ga.z), bfl(ga.w), bfh(ga.w)};
      float gnv[8] = {bfl(gn.x), bfh(gn.x), bfl(gn.y), bfh(gn.y),
                      bfl(gn.z), bfh(gn.z), bfl(gn.w), bfh(gn.w)};
#pragma unroll
      for (int e = 0; e < 8; ++e) {
        const float dap = sqrtf(fmaxf(fmaf(-2.f, gav[e], nj[e] + capr), 1e-12f));
        const float dan = sqrtf(fmaxf(fmaf(-2.f, gnv[e], nj[e] + cbpr), 1e-12f));
        s += fmaxf(dap - dan + MARGINV, 0.f);
      }
    }
  }
  for (int off = 32; off; off >>= 1) s += __shfl_xor(s, off);
  __shared__ float ps[4];
  const int w = t >> 6, lane = t & 63;
  if (lane == 0) ps[w] = s;
  __syncthreads();
  if (t == 0) {
    atomicAdd(acc, (ps[0] + ps[1]) + (ps[2] + ps[3]));  // device-scope (m20)
    __threadfence();
    unsigned int old = __hip_atomic_fetch_add(ticket, 1u, __ATOMIC_ACQ_REL,
                                              __HIP_MEMORY_SCOPE_AGENT);
    if (old == (unsigned int)(gridDim.x - 1)) {  // last block finalizes
      float total = __hip_atomic_load(acc, __ATOMIC_ACQUIRE, __HIP_MEMORY_SCOPE_AGENT);
      out[0] = total * (1.0f / ((float)BSZ * (float)BSZ));
    }
  }
}

// ---------------- Launch ----------------
extern "C" void kernel_launch(void* const* d_in, const int* in_sizes, int n_in,
                              void* d_out, int out_size, void* d_ws, size_t ws_size,
                              hipStream_t stream) {
  const float* feat = (const float*)d_in[0];
  const int* labels = (const int*)d_in[1];
  float* out = (float*)d_out;

  char* ws = (char*)d_ws;
  uint16_t* Gb     = (uint16_t*)ws;                               // 32 MB (bf16 G)
  uint8_t* Fq      = (uint8_t*)(ws + (size_t)33554432);           // 4 MB
  float* norm2     = (float*)(ws + (size_t)37748736);             // 16 KB
  float* sums      = (float*)(ws + (size_t)37748736 + 16384);     // 16 KB
  float* nv        = (float*)(ws + (size_t)37748736 + 32768);     // 16 KB
  int* pos_idx     = (int*)  (ws + (size_t)37748736 + 49152);     // 16 KB
  int* neg_idx     = (int*)  (ws + (size_t)37748736 + 65536);     // 16 KB
  float* acc       = (float*)(ws + (size_t)37748736 + 81920);     // 4 B
  unsigned int* tk = (unsigned int*)(ws + (size_t)37748736 + 81924);

  // JAX partitionable split: k_i = threefry(base_key=(0,42), (0, i))
  uint32_t k1a, k1b, k2a, k2b;
  threefry2x32(0u, 42u, 0u, 0u, k1a, k1b);  // k1 -> pos uniforms
  threefry2x32(0u, 42u, 0u, 1u, k2a, k2b);  // k2 -> neg uniforms

  prep_kernel<<<dim3(BSZ / 4), dim3(256), 0, stream>>>(feat, Fq, norm2, sums, nv, acc, tk);
  sample_kernel<<<dim3(BSZ), dim3(256), 0, stream>>>(labels, pos_idx, neg_idx, k1a, k1b, k2a, k2b);
  gemm_kernel<<<dim3(528), dim3(256), 0, stream>>>(Fq, Gb);
  loss_kernel<<<dim3(BSZ / LROWS), dim3(256), 0, stream>>>(Gb, norm2, sums, nv, pos_idx,
                                                           neg_idx, acc, tk, out);
}